// Round 5
// baseline (3747.883 us; speedup 1.0000x reference)
//
#include <hip/hip_runtime.h>
#include <math.h>

namespace {
constexpr int B_ = 128;
constexpr int N_ = 256;
constexpr int H_ = 128;
constexpr int M_TOTAL = B_ * N_;  // 32768 nodes
}

#define AS1 __attribute__((address_space(1)))
#define AS3 __attribute__((address_space(3)))

// async 16B global->LDS. LDS dest = wave-uniform base + lane*16 (HW-defined).
__device__ __forceinline__ void gl_lds16(const float* g, float* l) {
  __builtin_amdgcn_global_load_lds((const AS1 unsigned int*)g,
                                   (AS3 unsigned int*)l, 16, 0, 0);
}

// ---------------- weight reshape for scalar-load fourier ----------------
// in: W [2][O][I][8] -> out: Wsc [O/16][I][8][2][16]
// (out-group, input, harmonic, cos/sin, out-within-group)
template<int I, int O>
__global__ __launch_bounds__(256)
void wtr2_kernel(const float* __restrict__ in, float* __restrict__ out) {
  int idx = blockIdx.x * 256 + threadIdx.x;
  constexpr int TOTAL = 2 * O * I * 8;
  if (idx >= TOTAL) return;
  int g = idx & 7;
  int t = idx >> 3;
  int i = t % I;
  int t2 = t / I;
  int o = t2 % O;
  int s = t2 / O;
  out[(size_t)((((o >> 4) * I + i) * 8 + g) * 2 + s) * 16 + (o & 15)] = in[idx];
}

// ---------------- tiled transpose: in [M][K] -> out [K][M] ----------------
template<int K>
__global__ __launch_bounds__(256)
void transpose_kernel(const float* __restrict__ in, float* __restrict__ outT) {
  __shared__ float t[32][33];
  const int x0 = blockIdx.x * 32;  // node dim
  const int y0 = blockIdx.y * 32;  // feature dim
  const int c = threadIdx.x & 31, r8 = threadIdx.x >> 5;
  #pragma unroll
  for (int rr = 0; rr < 4; ++rr) {
    int r = r8 * 4 + rr;
    t[r][c] = in[(size_t)(x0 + r) * K + y0 + c];
  }
  __syncthreads();
  #pragma unroll
  for (int rr = 0; rr < 4; ++rr) {
    int r = r8 * 4 + rr;
    outT[(size_t)(y0 + r) * M_TOTAL + x0 + c] = t[c][r];
  }
}

// ---------------- Fourier-KAN linear, scalar-weight / no-LDS ----------------
// out[node][o] = sum_{i,g} cos(x[n][i]*(g+1))*W0[o][i][g] + sin(..)*W1[o][i][g]
// One lane = one node; blockIdx.y = out-group (16 outs). Weights are
// wave-uniform (blockIdx.y + loop counters) -> scalar loads, SGPR FMA operand.
// Features in-register: 1 sincos / input + 4-FMA rotation per harmonic.
template<int IN>
__global__ __launch_bounds__(256, 4)
void fourier5(const float* __restrict__ xT,   // [IN][M]
              const float* __restrict__ Wsc,  // [8][IN][8][2][16]
              float* __restrict__ out)        // [M][128]
{
  const int tid = threadIdx.x;
  const int node = blockIdx.x * 256 + tid;
  const int og = blockIdx.y;  // 0..7
  const float* __restrict__ wb = Wsc + (size_t)og * IN * 256;

  float acc[16];
  #pragma unroll
  for (int o = 0; o < 16; ++o) acc[o] = 0.f;

  float xv = xT[node];  // i = 0
  #pragma unroll 1
  for (int i = 0; i < IN; ++i) {
    float xn = 0.f;
    if (i + 1 < IN) xn = xT[(size_t)(i + 1) * M_TOTAL + node];
    float s1, c1;
    sincosf(xv, &s1, &c1);
    float ck = c1, sk = s1;  // k = 1
    const float* wi = wb + (size_t)i * 256;
    #pragma unroll
    for (int g = 0; g < 8; ++g) {
      const float* wg = wi + g * 32;
      #pragma unroll
      for (int o = 0; o < 16; ++o)
        acc[o] += ck * wg[o] + sk * wg[16 + o];
      // rotate by angle x: k -> k+1 (norm-preserving, well-conditioned)
      float cn = ck * c1 - sk * s1;
      sk = sk * c1 + ck * s1;
      ck = cn;
    }
    xv = xn;
  }

  float* po = out + (size_t)node * H_ + og * 16;  // one 64B line per lane
  float4 v0 = {acc[0], acc[1], acc[2], acc[3]};
  float4 v1 = {acc[4], acc[5], acc[6], acc[7]};
  float4 v2 = {acc[8], acc[9], acc[10], acc[11]};
  float4 v3 = {acc[12], acc[13], acc[14], acc[15]};
  *(float4*)(po + 0) = v0;
  *(float4*)(po + 4) = v1;
  *(float4*)(po + 8) = v2;
  *(float4*)(po + 12) = v3;
}

// ---------------- Aggregation + residual + leaky ----------------
// h_out[b][m][o] = leaky( sum_k A[b][k>>2][k&3][m] * f[b][k>>2][o] + h_in[b][m][o] )
// Block: 64 m x 128 o, 256 thr, per-thread 4m x 8o, K chunk 32, dbuf, async LDS.
__global__ __launch_bounds__(256)
void agg4(const float* __restrict__ A,     // [B][N][4][N]
          const float* __restrict__ f,     // [B][N][128]
          const float* __restrict__ h_in,  // [B][N][128]
          float* __restrict__ h_out)       // [B][N][128]
{
  __shared__ alignas(16) float As[2][32][64];    // 16 KB
  __shared__ alignas(16) float fsh[2][8][128];   // 8 KB
  const int tid = threadIdx.x;
  const int b = blockIdx.x >> 2;
  const int m0 = (blockIdx.x & 3) * 64;
  const int og = tid & 15;   // outs og*4, og*4+64
  const int mg = tid >> 4;   // m rows mg*4..+3
  const int wave = tid >> 6;

  float acc[4][8];
  #pragma unroll
  for (int i = 0; i < 4; ++i)
    #pragma unroll
    for (int j = 0; j < 8; ++j) acc[i][j] = 0.f;

  const float* Ab = A + (size_t)b * (N_ * 4 * N_) + m0;
  const float* fb = f + (size_t)b * (N_ * H_);

  // stage chunk 0
  #pragma unroll
  for (int q = 0; q < 2; ++q) {
    int v = q * 256 + tid;  // float4 index into [32][64]
    gl_lds16(Ab + (size_t)(v >> 4) * N_ + (v & 15) * 4,
             &As[0][0][0] + (size_t)(q * 256 + wave * 64) * 4);
  }
  gl_lds16(fb + (size_t)(tid >> 5) * H_ + (tid & 31) * 4,
           &fsh[0][0][0] + (size_t)(wave * 64) * 4);
  __syncthreads();

  int p = 0;
  for (int ch = 0; ch < 32; ++ch) {
    const int pn = p ^ 1;
    if (ch + 1 < 32) {
      const float* Asrc = Ab + (size_t)(ch + 1) * 32 * N_;
      #pragma unroll
      for (int q = 0; q < 2; ++q) {
        int v = q * 256 + tid;
        gl_lds16(Asrc + (size_t)(v >> 4) * N_ + (v & 15) * 4,
                 &As[pn][0][0] + (size_t)(q * 256 + wave * 64) * 4);
      }
      gl_lds16(fb + (size_t)((ch + 1) * 8 + (tid >> 5)) * H_ + (tid & 31) * 4,
               &fsh[pn][0][0] + (size_t)(wave * 64) * 4);
    }
    #pragma unroll
    for (int kk = 0; kk < 32; ++kk) {
      float4 a  = *(const float4*)&As[p][kk][mg * 4];
      float4 f0 = *(const float4*)&fsh[p][kk >> 2][og * 4];
      float4 f1 = *(const float4*)&fsh[p][kk >> 2][og * 4 + 64];
      float av[4] = {a.x, a.y, a.z, a.w};
      float fo[8] = {f0.x, f0.y, f0.z, f0.w, f1.x, f1.y, f1.z, f1.w};
      #pragma unroll
      for (int mi = 0; mi < 4; ++mi)
        #pragma unroll
        for (int oi = 0; oi < 8; ++oi)
          acc[mi][oi] += av[mi] * fo[oi];
    }
    __syncthreads();
    p ^= 1;
  }

  #pragma unroll
  for (int mi = 0; mi < 4; ++mi) {
    int row = b * N_ + m0 + mg * 4 + mi;
    const float* hr = &h_in[(size_t)row * H_];
    float* ho = &h_out[(size_t)row * H_];
    float4 r0 = *(const float4*)&hr[og * 4];
    float4 r1 = *(const float4*)&hr[og * 4 + 64];
    float4 o0, o1;
    float v;
    v = acc[mi][0] + r0.x; o0.x = v >= 0.f ? v : 0.01f * v;
    v = acc[mi][1] + r0.y; o0.y = v >= 0.f ? v : 0.01f * v;
    v = acc[mi][2] + r0.z; o0.z = v >= 0.f ? v : 0.01f * v;
    v = acc[mi][3] + r0.w; o0.w = v >= 0.f ? v : 0.01f * v;
    v = acc[mi][4] + r1.x; o1.x = v >= 0.f ? v : 0.01f * v;
    v = acc[mi][5] + r1.y; o1.y = v >= 0.f ? v : 0.01f * v;
    v = acc[mi][6] + r1.z; o1.z = v >= 0.f ? v : 0.01f * v;
    v = acc[mi][7] + r1.w; o1.w = v >= 0.f ? v : 0.01f * v;
    *(float4*)&ho[og * 4] = o0;
    *(float4*)&ho[og * 4 + 64] = o1;
  }
}

// ---------------- Masked mean pool + KAN head + sigmoid ----------------
__global__ __launch_bounds__(128)
void pool_kernel(const float* __restrict__ h,     // [B][N][128]
                 const int* __restrict__ mol,     // [B]
                 const float* __restrict__ Wout,  // [2][1][128][1]
                 const float* __restrict__ bout,  // [1][1]
                 float* __restrict__ out)         // [B]
{
  __shared__ float red[128];
  const int b = blockIdx.x;
  const int t = threadIdx.x;
  const int ms = mol[b];
  const float* hb = h + (size_t)b * N_ * H_;
  float sum = 0.f;
  for (int n = 0; n < ms; ++n) sum += hb[(size_t)n * H_ + t];
  float y = sum / (float)ms;
  float s1, c1;
  sincosf(y, &s1, &c1);
  red[t] = c1 * Wout[t] + s1 * Wout[H_ + t];
  __syncthreads();
  for (int sft = 64; sft > 0; sft >>= 1) {
    if (t < sft) red[t] += red[t + sft];
    __syncthreads();
  }
  if (t == 0) {
    float z = red[0] + bout[0];
    out[b] = 1.f / (1.f + expf(-z));
  }
}

extern "C" void kernel_launch(void* const* d_in, const int* in_sizes, int n_in,
                              void* d_out, int out_size, void* d_ws, size_t ws_size,
                              hipStream_t stream) {
  const float* V    = (const float*)d_in[0];
  const float* A    = (const float*)d_in[1];
  const int*   mol  = (const int*)d_in[2];
  const float* Win  = (const float*)d_in[3];
  const float* Wg   = (const float*)d_in[4];
  const float* Wout = (const float*)d_in[5];
  const float* bout = (const float*)d_in[6];
  float* out = (float*)d_out;

  const size_t BUF = (size_t)M_TOTAL * H_;           // 4M floats = 16 MB
  float* h      = (float*)d_ws;
  float* h2     = h  + BUF;
  float* f      = h2 + BUF;                          // also aliases VT (8 MB)
  float* hT     = f  + BUF;                          // [128][32768]
  float* wsc_in = hT + BUF;                          // [8][64][8][2][16]
  float* wsc_g0 = wsc_in + (size_t)2 * H_ * 64 * 8;  // [8][128][8][2][16]
  float* wsc_g1 = wsc_g0 + (size_t)2 * H_ * H_ * 8;
  float* VT     = f;  // [64][32768], dead before f is first written

  wtr2_kernel<64, 128><<<(2 * 128 * 64 * 8) / 256, 256, 0, stream>>>(Win, wsc_in);
  wtr2_kernel<128, 128><<<(2 * 128 * 128 * 8) / 256, 256, 0, stream>>>(Wg, wsc_g0);
  wtr2_kernel<128, 128><<<(2 * 128 * 128 * 8) / 256, 256, 0, stream>>>(
      Wg + (size_t)2 * 128 * 128 * 8, wsc_g1);

  // layer 0: V -> VT -> h
  transpose_kernel<64><<<dim3(M_TOTAL / 32, 2), 256, 0, stream>>>(V, VT);
  fourier5<64><<<dim3(M_TOTAL / 256, 8), 256, 0, stream>>>(VT, wsc_in, h);

  float* hc = h;
  float* hn = h2;
  const float* wsc_g[2] = {wsc_g0, wsc_g1};
  for (int l = 0; l < 2; ++l) {
    transpose_kernel<128><<<dim3(M_TOTAL / 32, 4), 256, 0, stream>>>(hc, hT);
    fourier5<128><<<dim3(M_TOTAL / 256, 8), 256, 0, stream>>>(hT, wsc_g[l], f);
    agg4<<<B_ * 4, 256, 0, stream>>>(A, f, hc, hn);
    float* tmp = hc; hc = hn; hn = tmp;
  }

  pool_kernel<<<B_, 128, 0, stream>>>(hc, mol, Wout, bout, out);
}

// Round 6
// 1075.770 us; speedup vs baseline: 3.4839x; 3.4839x over previous
//
#include <hip/hip_runtime.h>
#include <math.h>

namespace {
constexpr int B_ = 128;
constexpr int N_ = 256;
constexpr int H_ = 128;
constexpr int M_TOTAL = B_ * N_;  // 32768 nodes
}

#define AS1 __attribute__((address_space(1)))
#define AS3 __attribute__((address_space(3)))

// async 16B global->LDS. LDS dest = wave-uniform base + lane*16 (HW-defined).
__device__ __forceinline__ void gl_lds16(const float* g, float* l) {
  __builtin_amdgcn_global_load_lds((const AS1 unsigned int*)g,
                                   (AS3 unsigned int*)l, 16, 0, 0);
}

// ---------------- weight pre-transpose ----------------
// in: W [2][O][I][8]  ->  out: Wt [I*8][2][O]   (pair-major, sin/cos, out)
template<int I, int O>
__global__ __launch_bounds__(256)
void wtr_kernel(const float* __restrict__ in, float* __restrict__ out) {
  int idx = blockIdx.x * 256 + threadIdx.x;
  constexpr int TOTAL = 2 * O * I * 8;
  if (idx >= TOTAL) return;
  int g = idx & 7;
  int t = idx >> 3;
  int i = t % I;
  int t2 = t / I;
  int o = t2 % O;
  int s = t2 / O;
  out[(size_t)((i * 8 + g) * 2 + s) * O + o] = in[idx];
}

// ---------------- elementwise float4 add (combine split-K halves) ----------
__global__ __launch_bounds__(256)
void add4_kernel(const float* __restrict__ a, const float* __restrict__ b,
                 float* __restrict__ o, int n4) {
  int i = blockIdx.x * 256 + threadIdx.x;
  int stride = gridDim.x * 256;
  for (; i < n4; i += stride) {
    float4 x = ((const float4*)a)[i];
    float4 y = ((const float4*)b)[i];
    float4 r = {x.x + y.x, x.y + y.y, x.z + y.z, x.w + y.w};
    ((float4*)o)[i] = r;
  }
}

// ---------------- Fourier-KAN linear, split-K=2, 8nx8o tiles ----------------
// out_half[node][o] = sum over half the inputs of
//   cos(x[n][i]*(g+1))*W0[o][i][g] + sin(..)*W1[o][i][g]
// Block: 128 nodes x 128 outs, 256 thr, per-thread 8n x 8o.
// Chunk = 1 input (8 pairs), double-buffered. LDS 32 KB.
// blockIdx: bit0 = K-half, rest = node tile. Grid 512 = 2 blocks/CU.
template<int IN>
__global__ __launch_bounds__(256, 3)
void fourier6(const float* __restrict__ x,    // [M][IN]
              const float* __restrict__ Wt,   // [IN*8][2][128]
              float* __restrict__ out0,       // [M][128] partial (half 0)
              float* __restrict__ out1)       // [M][128] partial (half 1)
{
  constexpr int HIN = IN / 2;                     // inputs per half = chunks
  __shared__ alignas(16) float wl[2][8][2][128];  // 16 KB
  __shared__ alignas(16) float fC[2][8][128];     // 8 KB
  __shared__ alignas(16) float fS[2][8][128];     // 8 KB

  const int tid = threadIdx.x;
  const int khalf = blockIdx.x & 1;
  const int node0 = (blockIdx.x >> 1) * 128;
  const int og = tid & 15;      // outs og*4..+3 and og*4+64..+67
  const int ng = tid >> 4;      // 0..15: nodes ng*8..+7
  const int lane = tid & 63;
  const int wave = tid >> 6;
  const int fnode = tid & 127;  // feature-staging node
  const int fhi = tid >> 7;     // 0: harmonics k=1..4, 1: k=5..8

  float* __restrict__ out = khalf ? out1 : out0;
  const float* wb = Wt + (size_t)khalf * HIN * 2048;  // 8 pairs*256 per input
  const float* xrow = x + (size_t)(node0 + fnode) * IN + khalf * HIN;

  float acc[8][8];
  #pragma unroll
  for (int a = 0; a < 8; ++a)
    #pragma unroll
    for (int b = 0; b < 8; ++b) acc[a][b] = 0.f;

  // write features (cos/sin of k*x, k=1..8 split by fhi) into buffer pb
  auto put_feats = [&](int pb, float xx) {
    float s1, c1;
    sincosf(xx, &s1, &c1);
    float ck, sk;
    if (fhi == 0) {
      ck = c1; sk = s1;                              // k=1
    } else {
      float c2 = c1 * c1 - s1 * s1, s2 = 2.f * c1 * s1;
      float c4 = c2 * c2 - s2 * s2, s4 = 2.f * s2 * c2;
      ck = c4 * c1 - s4 * s1;                        // k=5
      sk = s4 * c1 + c4 * s1;
    }
    const int g0 = fhi * 4;
    #pragma unroll
    for (int t = 0; t < 4; ++t) {
      fC[pb][g0 + t][fnode] = ck;
      fS[pb][g0 + t][fnode] = sk;
      float cn = ck * c1 - sk * s1;
      sk = sk * c1 + ck * s1;
      ck = cn;
    }
  };

  // ---- prologue: chunk 0
  #pragma unroll
  for (int q = 0; q < 2; ++q) {
    int u = q * 256 + tid;
    gl_lds16(wb + (size_t)u * 4,
             &wl[0][0][0][0] + (size_t)(q * 256 + wave * 64) * 4);
  }
  float xv = xrow[0];
  float xnext = (HIN > 1) ? xrow[1] : 0.f;
  put_feats(0, xv);
  __syncthreads();

  int p = 0;
  for (int ic = 0; ic < HIN; ++ic) {
    const int pn = p ^ 1;
    if (ic + 1 < HIN) {
      const float* wsrc = wb + (size_t)(ic + 1) * 2048;
      #pragma unroll
      for (int q = 0; q < 2; ++q) {
        int u = q * 256 + tid;
        gl_lds16(wsrc + (size_t)u * 4,
                 &wl[pn][0][0][0] + (size_t)(q * 256 + wave * 64) * 4);
      }
      put_feats(pn, xnext);
      if (ic + 2 < HIN) xnext = xrow[ic + 2];
    }
    // ---- compute on buf p: 8 pairs x (8 nodes x 8 outs x {cos,sin})
    #pragma unroll 2
    for (int j = 0; j < 8; ++j) {
      float4 fc0 = *(const float4*)&fC[p][j][ng * 8];
      float4 fc1 = *(const float4*)&fC[p][j][ng * 8 + 4];
      float4 fs0 = *(const float4*)&fS[p][j][ng * 8];
      float4 fs1 = *(const float4*)&fS[p][j][ng * 8 + 4];
      float4 w0a = *(const float4*)&wl[p][j][0][og * 4];
      float4 w0b = *(const float4*)&wl[p][j][0][og * 4 + 64];
      float4 w1a = *(const float4*)&wl[p][j][1][og * 4];
      float4 w1b = *(const float4*)&wl[p][j][1][og * 4 + 64];
      float fcv[8] = {fc0.x, fc0.y, fc0.z, fc0.w, fc1.x, fc1.y, fc1.z, fc1.w};
      float fsv[8] = {fs0.x, fs0.y, fs0.z, fs0.w, fs1.x, fs1.y, fs1.z, fs1.w};
      float wa0[4] = {w0a.x, w0a.y, w0a.z, w0a.w};
      float wb0[4] = {w0b.x, w0b.y, w0b.z, w0b.w};
      float wa1[4] = {w1a.x, w1a.y, w1a.z, w1a.w};
      float wb1[4] = {w1b.x, w1b.y, w1b.z, w1b.w};
      #pragma unroll
      for (int nd = 0; nd < 8; ++nd) {
        #pragma unroll
        for (int oo = 0; oo < 4; ++oo) {
          acc[nd][oo]     += fcv[nd] * wa0[oo] + fsv[nd] * wa1[oo];
          acc[nd][4 + oo] += fcv[nd] * wb0[oo] + fsv[nd] * wb1[oo];
        }
      }
    }
    __syncthreads();
    p ^= 1;
  }

  #pragma unroll
  for (int nd = 0; nd < 8; ++nd) {
    int row = node0 + ng * 8 + nd;
    float4 ra = {acc[nd][0], acc[nd][1], acc[nd][2], acc[nd][3]};
    float4 rb = {acc[nd][4], acc[nd][5], acc[nd][6], acc[nd][7]};
    *(float4*)&out[(size_t)row * H_ + og * 4] = ra;
    *(float4*)&out[(size_t)row * H_ + og * 4 + 64] = rb;
  }
}

// ---------------- Aggregation + residual + leaky, 8mx8o tiles ----------------
// f = f0 + f1 fused during staging. Hoisted f-reads (reused across 4 kk).
// h_out[b][m][o] = leaky( sum_k A[b][k>>2][k&3][m] * (f0+f1)[b][k>>2][o]
//                         + h_in[b][m][o] )
// Block: 64 m x 128 o, 128 thr (2 waves), per-thread 8m x 8o. K chunk 32, dbuf.
__global__ __launch_bounds__(128, 2)
void agg5(const float* __restrict__ A,     // [B][N][4][N]
          const float* __restrict__ f0,    // [B][N][128] partial
          const float* __restrict__ f1,    // [B][N][128] partial
          const float* __restrict__ h_in,  // [B][N][128]
          float* __restrict__ h_out)       // [B][N][128]
{
  __shared__ alignas(16) float As[2][32][64];    // 16 KB
  __shared__ alignas(16) float fsh[2][8][128];   // 8 KB
  const int tid = threadIdx.x;
  const int b = blockIdx.x >> 2;
  const int m0 = (blockIdx.x & 3) * 64;
  const int og = tid & 15;   // outs og*4, og*4+64
  const int mg = tid >> 4;   // 0..7: m rows mg*8..+7
  const int wave = tid >> 6;

  float acc[8][8];
  #pragma unroll
  for (int i = 0; i < 8; ++i)
    #pragma unroll
    for (int j = 0; j < 8; ++j) acc[i][j] = 0.f;

  const float* Ab  = A  + (size_t)b * (N_ * 4 * N_) + m0;
  const float* f0b = f0 + (size_t)b * (N_ * H_);
  const float* f1b = f1 + (size_t)b * (N_ * H_);

  // ---- prologue chunk 0
  float4 u0[2], u1[2];
  #pragma unroll
  for (int q = 0; q < 2; ++q) {
    int u = q * 128 + tid;
    u0[q] = *(const float4*)(f0b + (size_t)(u >> 5) * H_ + (u & 31) * 4);
    u1[q] = *(const float4*)(f1b + (size_t)(u >> 5) * H_ + (u & 31) * 4);
  }
  #pragma unroll
  for (int q = 0; q < 4; ++q) {
    int v = q * 128 + tid;  // float4 index into [32][64]
    gl_lds16(Ab + (size_t)(v >> 4) * N_ + (v & 15) * 4,
             &As[0][0][0] + (size_t)(q * 128 + wave * 64) * 4);
  }
  #pragma unroll
  for (int q = 0; q < 2; ++q) {
    int u = q * 128 + tid;
    float4 s = {u0[q].x + u1[q].x, u0[q].y + u1[q].y,
                u0[q].z + u1[q].z, u0[q].w + u1[q].w};
    *(float4*)&fsh[0][u >> 5][(u & 31) * 4] = s;
  }
  __syncthreads();

  int p = 0;
  for (int ch = 0; ch < 32; ++ch) {
    const int pn = p ^ 1;
    float4 v0[2], v1[2];
    if (ch + 1 < 32) {
      // issue f loads to regs first, then async A staging
      #pragma unroll
      for (int q = 0; q < 2; ++q) {
        int u = q * 128 + tid;
        v0[q] = *(const float4*)(f0b +
                   (size_t)((ch + 1) * 8 + (u >> 5)) * H_ + (u & 31) * 4);
        v1[q] = *(const float4*)(f1b +
                   (size_t)((ch + 1) * 8 + (u >> 5)) * H_ + (u & 31) * 4);
      }
      const float* Asrc = Ab + (size_t)(ch + 1) * 32 * N_;
      #pragma unroll
      for (int q = 0; q < 4; ++q) {
        int v = q * 128 + tid;
        gl_lds16(Asrc + (size_t)(v >> 4) * N_ + (v & 15) * 4,
                 &As[pn][0][0] + (size_t)(q * 128 + wave * 64) * 4);
      }
    }
    #pragma unroll 2
    for (int q8 = 0; q8 < 8; ++q8) {
      float4 g0 = *(const float4*)&fsh[p][q8][og * 4];
      float4 g1 = *(const float4*)&fsh[p][q8][og * 4 + 64];
      float fo[8] = {g0.x, g0.y, g0.z, g0.w, g1.x, g1.y, g1.z, g1.w};
      #pragma unroll
      for (int k4 = 0; k4 < 4; ++k4) {
        int kk = q8 * 4 + k4;
        float4 a0 = *(const float4*)&As[p][kk][mg * 8];
        float4 a1 = *(const float4*)&As[p][kk][mg * 8 + 4];
        float am[8] = {a0.x, a0.y, a0.z, a0.w, a1.x, a1.y, a1.z, a1.w};
        #pragma unroll
        for (int mi = 0; mi < 8; ++mi)
          #pragma unroll
          for (int oi = 0; oi < 8; ++oi)
            acc[mi][oi] += am[mi] * fo[oi];
      }
    }
    if (ch + 1 < 32) {
      #pragma unroll
      for (int q = 0; q < 2; ++q) {
        int u = q * 128 + tid;
        float4 s = {v0[q].x + v1[q].x, v0[q].y + v1[q].y,
                    v0[q].z + v1[q].z, v0[q].w + v1[q].w};
        *(float4*)&fsh[pn][u >> 5][(u & 31) * 4] = s;
      }
    }
    __syncthreads();
    p ^= 1;
  }

  #pragma unroll
  for (int mi = 0; mi < 8; ++mi) {
    int row = b * N_ + m0 + mg * 8 + mi;
    const float* hr = &h_in[(size_t)row * H_];
    float* ho = &h_out[(size_t)row * H_];
    float4 r0 = *(const float4*)&hr[og * 4];
    float4 r1 = *(const float4*)&hr[og * 4 + 64];
    float4 o0, o1;
    float v;
    v = acc[mi][0] + r0.x; o0.x = v >= 0.f ? v : 0.01f * v;
    v = acc[mi][1] + r0.y; o0.y = v >= 0.f ? v : 0.01f * v;
    v = acc[mi][2] + r0.z; o0.z = v >= 0.f ? v : 0.01f * v;
    v = acc[mi][3] + r0.w; o0.w = v >= 0.f ? v : 0.01f * v;
    v = acc[mi][4] + r1.x; o1.x = v >= 0.f ? v : 0.01f * v;
    v = acc[mi][5] + r1.y; o1.y = v >= 0.f ? v : 0.01f * v;
    v = acc[mi][6] + r1.z; o1.z = v >= 0.f ? v : 0.01f * v;
    v = acc[mi][7] + r1.w; o1.w = v >= 0.f ? v : 0.01f * v;
    *(float4*)&ho[og * 4] = o0;
    *(float4*)&ho[og * 4 + 64] = o1;
  }
}

// ---------------- Masked mean pool + KAN head + sigmoid ----------------
__global__ __launch_bounds__(128)
void pool_kernel(const float* __restrict__ h,     // [B][N][128]
                 const int* __restrict__ mol,     // [B]
                 const float* __restrict__ Wout,  // [2][1][128][1]
                 const float* __restrict__ bout,  // [1][1]
                 float* __restrict__ out)         // [B]
{
  __shared__ float red[128];
  const int b = blockIdx.x;
  const int t = threadIdx.x;
  const int ms = mol[b];
  const float* hb = h + (size_t)b * N_ * H_;
  float sum = 0.f;
  for (int n = 0; n < ms; ++n) sum += hb[(size_t)n * H_ + t];
  float y = sum / (float)ms;
  float s1, c1;
  sincosf(y, &s1, &c1);
  red[t] = c1 * Wout[t] + s1 * Wout[H_ + t];
  __syncthreads();
  for (int sft = 64; sft > 0; sft >>= 1) {
    if (t < sft) red[t] += red[t + sft];
    __syncthreads();
  }
  if (t == 0) {
    float z = red[0] + bout[0];
    out[b] = 1.f / (1.f + expf(-z));
  }
}

extern "C" void kernel_launch(void* const* d_in, const int* in_sizes, int n_in,
                              void* d_out, int out_size, void* d_ws, size_t ws_size,
                              hipStream_t stream) {
  const float* V    = (const float*)d_in[0];
  const float* A    = (const float*)d_in[1];
  const int*   mol  = (const int*)d_in[2];
  const float* Win  = (const float*)d_in[3];
  const float* Wg   = (const float*)d_in[4];
  const float* Wout = (const float*)d_in[5];
  const float* bout = (const float*)d_in[6];
  float* out = (float*)d_out;

  const size_t BUF = (size_t)M_TOTAL * H_;           // 4M floats = 16 MB
  float* h     = (float*)d_ws;
  float* h2    = h  + BUF;
  float* f0    = h2 + BUF;
  float* f1    = f0 + BUF;
  float* wt_in = f1 + BUF;                           // [512][2][128]
  float* wt_g0 = wt_in + 512 * 2 * H_;               // [1024][2][128]
  float* wt_g1 = wt_g0 + 1024 * 2 * H_;

  wtr_kernel<64, 128><<<(2 * 128 * 64 * 8) / 256, 256, 0, stream>>>(Win, wt_in);
  wtr_kernel<128, 128><<<(2 * 128 * 128 * 8) / 256, 256, 0, stream>>>(Wg, wt_g0);
  wtr_kernel<128, 128><<<(2 * 128 * 128 * 8) / 256, 256, 0, stream>>>(
      Wg + (size_t)2 * 128 * 128 * 8, wt_g1);

  // layer 0: split-K fourier into f0/f1, combine into h
  fourier6<64><<<(M_TOTAL / 128) * 2, 256, 0, stream>>>(V, wt_in, f0, f1);
  add4_kernel<<<2048, 256, 0, stream>>>(f0, f1, h, (int)(BUF / 4));

  float* hc = h;
  float* hn = h2;
  const float* wt_g[2] = {wt_g0, wt_g1};
  for (int l = 0; l < 2; ++l) {
    fourier6<128><<<(M_TOTAL / 128) * 2, 256, 0, stream>>>(hc, wt_g[l], f0, f1);
    agg5<<<B_ * 4, 128, 0, stream>>>(A, f0, f1, hc, hn);
    float* tmp = hc; hc = hn; hn = tmp;
  }

  pool_kernel<<<B_, 128, 0, stream>>>(hc, mol, Wout, bout, out);
}

// Round 7
// 979.395 us; speedup vs baseline: 3.8267x; 1.0984x over previous
//
#include <hip/hip_runtime.h>
#include <math.h>

namespace {
constexpr int B_ = 128;
constexpr int N_ = 256;
constexpr int H_ = 128;
constexpr int M_TOTAL = B_ * N_;  // 32768 nodes
}

#define AS1 __attribute__((address_space(1)))
#define AS3 __attribute__((address_space(3)))

// async 16B global->LDS. LDS dest = wave-uniform base + lane*16 (HW-defined).
__device__ __forceinline__ void gl_lds16(const float* g, float* l) {
  __builtin_amdgcn_global_load_lds((const AS1 unsigned int*)g,
                                   (AS3 unsigned int*)l, 16, 0, 0);
}

// ---------------- weight pre-transpose ----------------
// in: W [2][O][I][8]  ->  out: Wt [I*8][2][O]   (pair-major, sin/cos, out)
template<int I, int O>
__global__ __launch_bounds__(256)
void wtr_kernel(const float* __restrict__ in, float* __restrict__ out) {
  int idx = blockIdx.x * 256 + threadIdx.x;
  constexpr int TOTAL = 2 * O * I * 8;
  if (idx >= TOTAL) return;
  int g = idx & 7;
  int t = idx >> 3;
  int i = t % I;
  int t2 = t / I;
  int o = t2 % O;
  int s = t2 / O;
  out[(size_t)((i * 8 + g) * 2 + s) * O + o] = in[idx];
}

// ---------------- Fourier-KAN linear, agg-shaped ----------------
// out[node][o] = sum_{i,g} cos(x[n][i]*(g+1))*W0[o][i][g] + sin(..)*W1[o][i][g]
// Block: 64 nodes x 128 outs, 256 thr, per-thread 4n x 8o (32 accs: stays in
// arch VGPRs - 64 accs provably forced AGPR read-modify-write, 3x VALU).
// Chunk = 2 inputs = 16 pairs -> per chunk-wave: 1024 FMA, 96 ds_read_b128,
// 4 gl_lds16, 1 barrier  == the proven agg3 runtime shape.
// Features (sincos + 3 rotations) computed AFTER the compute loop, role-split
// over the 4 waves: wave w handles (input fil=w>>1, harmonics fhi=w&1).
template<int IN>
__global__ __launch_bounds__(256, 4)
void fourier8(const float* __restrict__ x,    // [M][IN]
              const float* __restrict__ Wt,   // [IN*8][2][128]
              float* __restrict__ out)        // [M][128]
{
  constexpr int CHUNKS = IN / 2;
  __shared__ alignas(16) float wl[2][16][2][128];  // 32 KB
  __shared__ alignas(16) float fC[2][16][64];      // 8 KB
  __shared__ alignas(16) float fS[2][16][64];      // 8 KB

  const int tid = threadIdx.x;
  const int node0 = blockIdx.x * 64;
  const int og = tid & 15;      // outs og*4..+3 and og*4+64..+67
  const int ng = tid >> 4;      // 0..15: nodes ng*4..+3
  const int lane = tid & 63;
  const int wave = tid >> 6;
  const int fnode = tid & 63;   // feature-staging node
  const int fil = wave >> 1;    // input-within-chunk 0/1
  const int fhi = wave & 1;     // 0: harmonics k=1..4, 1: k=5..8

  const float* xrow = x + (size_t)(node0 + fnode) * IN;

  float acc[4][8];
  #pragma unroll
  for (int a = 0; a < 4; ++a)
    #pragma unroll
    for (int b = 0; b < 8; ++b) acc[a][b] = 0.f;

  // features for this thread's (fil, fhi) role into buffer pb
  auto put_feats = [&](int pb, float xx) {
    float s1, c1;
    sincosf(xx, &s1, &c1);
    float ck, sk;
    if (fhi == 0) {
      ck = c1; sk = s1;                              // k=1
    } else {
      float c2 = c1 * c1 - s1 * s1, s2 = 2.f * c1 * s1;
      float c4 = c2 * c2 - s2 * s2, s4 = 2.f * s2 * c2;
      ck = c4 * c1 - s4 * s1;                        // k=5
      sk = s4 * c1 + c4 * s1;
    }
    const int r0 = fil * 8 + fhi * 4;
    #pragma unroll
    for (int t = 0; t < 4; ++t) {
      fC[pb][r0 + t][fnode] = ck;
      fS[pb][r0 + t][fnode] = sk;
      float cn = ck * c1 - sk * s1;
      sk = sk * c1 + ck * s1;
      ck = cn;
    }
  };

  // stage chunk ic's weights (16 pairs x 2 x 128 = 4096 floats) into wl[pb]
  auto stage_w = [&](int pb, int ic) {
    const float* wsrc = Wt + (size_t)ic * 4096;
    float* wdst = &wl[pb][0][0][0];
    #pragma unroll
    for (int q = 0; q < 4; ++q) {
      gl_lds16(wsrc + (size_t)(q * 256 + tid) * 4,
               wdst + (size_t)(q * 1024 + wave * 256) + 0);  // +lane*4 by HW
    }
  };

  // ---- prologue: chunk 0
  stage_w(0, 0);
  float xv = xrow[fil];
  float xn = (CHUNKS > 1) ? xrow[2 + fil] : 0.f;
  put_feats(0, xv);
  __syncthreads();

  int p = 0;
  for (int ic = 0; ic < CHUNKS; ++ic) {
    const int pn = p ^ 1;
    if (ic + 1 < CHUNKS) stage_w(pn, ic + 1);
    float xn2 = (ic + 2 < CHUNKS) ? xrow[2 * (ic + 2) + fil] : 0.f;
    // ---- compute on buf p: 16 pairs x (4 nodes x 8 outs x {cos,sin})
    #pragma unroll 2
    for (int j = 0; j < 16; ++j) {
      float4 fc = *(const float4*)&fC[p][j][ng * 4];
      float4 fs = *(const float4*)&fS[p][j][ng * 4];
      float4 w0a = *(const float4*)&wl[p][j][0][og * 4];
      float4 w0b = *(const float4*)&wl[p][j][0][og * 4 + 64];
      float4 w1a = *(const float4*)&wl[p][j][1][og * 4];
      float4 w1b = *(const float4*)&wl[p][j][1][og * 4 + 64];
      float fcv[4] = {fc.x, fc.y, fc.z, fc.w};
      float fsv[4] = {fs.x, fs.y, fs.z, fs.w};
      float wa0[4] = {w0a.x, w0a.y, w0a.z, w0a.w};
      float wb0[4] = {w0b.x, w0b.y, w0b.z, w0b.w};
      float wa1[4] = {w1a.x, w1a.y, w1a.z, w1a.w};
      float wb1[4] = {w1b.x, w1b.y, w1b.z, w1b.w};
      #pragma unroll
      for (int nd = 0; nd < 4; ++nd) {
        #pragma unroll
        for (int oo = 0; oo < 4; ++oo) {
          acc[nd][oo]     += fcv[nd] * wa0[oo] + fsv[nd] * wa1[oo];
          acc[nd][4 + oo] += fcv[nd] * wb0[oo] + fsv[nd] * wb1[oo];
        }
      }
    }
    // ---- features for chunk ic+1 (post-compute: off the pre-FMA stall path)
    if (ic + 1 < CHUNKS) put_feats(pn, xn);
    xn = xn2;
    __syncthreads();
    p ^= 1;
  }

  #pragma unroll
  for (int nd = 0; nd < 4; ++nd) {
    int row = node0 + ng * 4 + nd;
    float4 ra = {acc[nd][0], acc[nd][1], acc[nd][2], acc[nd][3]};
    float4 rb = {acc[nd][4], acc[nd][5], acc[nd][6], acc[nd][7]};
    *(float4*)&out[(size_t)row * H_ + og * 4] = ra;
    *(float4*)&out[(size_t)row * H_ + og * 4 + 64] = rb;
  }
}

// ---------------- Aggregation + residual + leaky ----------------
// h_out[b][m][o] = leaky( sum_k A[b][k>>2][k&3][m] * f[b][k>>2][o] + h_in[b][m][o] )
// Block: 64 m x 128 o, 256 thr, per-thread 4m x 8o, K chunk 32, dbuf, async LDS.
__global__ __launch_bounds__(256)
void agg2(const float* __restrict__ A,     // [B][N][4][N]
          const float* __restrict__ f,     // [B][N][128]
          const float* __restrict__ h_in,  // [B][N][128]
          float* __restrict__ h_out)       // [B][N][128]
{
  __shared__ alignas(16) float As[2][32][64];    // 16 KB
  __shared__ alignas(16) float fsh[2][8][128];   // 8 KB
  const int tid = threadIdx.x;
  const int b = blockIdx.x >> 2;
  const int m0 = (blockIdx.x & 3) * 64;
  const int og = tid & 15;   // outs og*4, og*4+64
  const int mg = tid >> 4;   // m rows mg*4..+3
  const int wave = tid >> 6;

  float acc[4][8];
  #pragma unroll
  for (int i = 0; i < 4; ++i)
    #pragma unroll
    for (int j = 0; j < 8; ++j) acc[i][j] = 0.f;

  const float* Ab = A + (size_t)b * (N_ * 4 * N_) + m0;
  const float* fb = f + (size_t)b * (N_ * H_);

  // stage chunk 0
  #pragma unroll
  for (int q = 0; q < 2; ++q) {
    int v = q * 256 + tid;  // float4 index into [32][64]
    gl_lds16(Ab + (size_t)(v >> 4) * N_ + (v & 15) * 4,
             &As[0][0][0] + (size_t)(q * 256 + wave * 64) * 4);
  }
  gl_lds16(fb + (size_t)(tid >> 5) * H_ + (tid & 31) * 4,
           &fsh[0][0][0] + (size_t)(wave * 64) * 4);
  __syncthreads();

  int p = 0;
  for (int ch = 0; ch < 32; ++ch) {
    const int pn = p ^ 1;
    if (ch + 1 < 32) {
      const float* Asrc = Ab + (size_t)(ch + 1) * 32 * N_;
      #pragma unroll
      for (int q = 0; q < 2; ++q) {
        int v = q * 256 + tid;
        gl_lds16(Asrc + (size_t)(v >> 4) * N_ + (v & 15) * 4,
                 &As[pn][0][0] + (size_t)(q * 256 + wave * 64) * 4);
      }
      gl_lds16(fb + (size_t)((ch + 1) * 8 + (tid >> 5)) * H_ + (tid & 31) * 4,
               &fsh[pn][0][0] + (size_t)(wave * 64) * 4);
    }
    #pragma unroll
    for (int kk = 0; kk < 32; ++kk) {
      float4 a  = *(const float4*)&As[p][kk][mg * 4];
      float4 f0 = *(const float4*)&fsh[p][kk >> 2][og * 4];
      float4 f1 = *(const float4*)&fsh[p][kk >> 2][og * 4 + 64];
      float av[4] = {a.x, a.y, a.z, a.w};
      float fo[8] = {f0.x, f0.y, f0.z, f0.w, f1.x, f1.y, f1.z, f1.w};
      #pragma unroll
      for (int mi = 0; mi < 4; ++mi)
        #pragma unroll
        for (int oi = 0; oi < 8; ++oi)
          acc[mi][oi] += av[mi] * fo[oi];
    }
    __syncthreads();
    p ^= 1;
  }

  #pragma unroll
  for (int mi = 0; mi < 4; ++mi) {
    int row = b * N_ + m0 + mg * 4 + mi;
    const float* hr = &h_in[(size_t)row * H_];
    float* ho = &h_out[(size_t)row * H_];
    float4 r0 = *(const float4*)&hr[og * 4];
    float4 r1 = *(const float4*)&hr[og * 4 + 64];
    float4 o0, o1;
    float v;
    v = acc[mi][0] + r0.x; o0.x = v >= 0.f ? v : 0.01f * v;
    v = acc[mi][1] + r0.y; o0.y = v >= 0.f ? v : 0.01f * v;
    v = acc[mi][2] + r0.z; o0.z = v >= 0.f ? v : 0.01f * v;
    v = acc[mi][3] + r0.w; o0.w = v >= 0.f ? v : 0.01f * v;
    v = acc[mi][4] + r1.x; o1.x = v >= 0.f ? v : 0.01f * v;
    v = acc[mi][5] + r1.y; o1.y = v >= 0.f ? v : 0.01f * v;
    v = acc[mi][6] + r1.z; o1.z = v >= 0.f ? v : 0.01f * v;
    v = acc[mi][7] + r1.w; o1.w = v >= 0.f ? v : 0.01f * v;
    *(float4*)&ho[og * 4] = o0;
    *(float4*)&ho[og * 4 + 64] = o1;
  }
}

// ---------------- Masked mean pool + KAN head + sigmoid ----------------
__global__ __launch_bounds__(128)
void pool_kernel(const float* __restrict__ h,     // [B][N][128]
                 const int* __restrict__ mol,     // [B]
                 const float* __restrict__ Wout,  // [2][1][128][1]
                 const float* __restrict__ bout,  // [1][1]
                 float* __restrict__ out)         // [B]
{
  __shared__ float red[128];
  const int b = blockIdx.x;
  const int t = threadIdx.x;
  const int ms = mol[b];
  const float* hb = h + (size_t)b * N_ * H_;
  float sum = 0.f;
  for (int n = 0; n < ms; ++n) sum += hb[(size_t)n * H_ + t];
  float y = sum / (float)ms;
  float s1, c1;
  sincosf(y, &s1, &c1);
  red[t] = c1 * Wout[t] + s1 * Wout[H_ + t];
  __syncthreads();
  for (int sft = 64; sft > 0; sft >>= 1) {
    if (t < sft) red[t] += red[t + sft];
    __syncthreads();
  }
  if (t == 0) {
    float z = red[0] + bout[0];
    out[b] = 1.f / (1.f + expf(-z));
  }
}

extern "C" void kernel_launch(void* const* d_in, const int* in_sizes, int n_in,
                              void* d_out, int out_size, void* d_ws, size_t ws_size,
                              hipStream_t stream) {
  const float* V    = (const float*)d_in[0];
  const float* A    = (const float*)d_in[1];
  const int*   mol  = (const int*)d_in[2];
  const float* Win  = (const float*)d_in[3];
  const float* Wg   = (const float*)d_in[4];
  const float* Wout = (const float*)d_in[5];
  const float* bout = (const float*)d_in[6];
  float* out = (float*)d_out;

  const size_t BUF = (size_t)M_TOTAL * H_;           // 4M floats = 16 MB
  float* h     = (float*)d_ws;
  float* h2    = h  + BUF;
  float* f     = h2 + BUF;
  float* wt_in = f  + BUF;                           // [512][2][128]
  float* wt_g0 = wt_in + 512 * 2 * H_;               // [1024][2][128]
  float* wt_g1 = wt_g0 + 1024 * 2 * H_;

  wtr_kernel<64, 128><<<(2 * 128 * 64 * 8) / 256, 256, 0, stream>>>(Win, wt_in);
  wtr_kernel<128, 128><<<(2 * 128 * 128 * 8) / 256, 256, 0, stream>>>(Wg, wt_g0);
  wtr_kernel<128, 128><<<(2 * 128 * 128 * 8) / 256, 256, 0, stream>>>(
      Wg + (size_t)2 * 128 * 128 * 8, wt_g1);

  fourier8<64><<<M_TOTAL / 64, 256, 0, stream>>>(V, wt_in, h);

  float* hc = h;
  float* hn = h2;
  const float* wt_g[2] = {wt_g0, wt_g1};
  for (int l = 0; l < 2; ++l) {
    fourier8<128><<<M_TOTAL / 64, 256, 0, stream>>>(hc, wt_g[l], f);
    agg2<<<B_ * 4, 256, 0, stream>>>(A, f, hc, hn);
    float* tmp = hc; hc = hn; hn = tmp;
  }

  pool_kernel<<<B_, 128, 0, stream>>>(hc, mol, Wout, bout, out);
}